// Round 2
// baseline (20.030 us; speedup 1.0000x reference)
//
#include <hip/hip_runtime.h>
#include <hip/hip_bf16.h>

#define EMB    450
#define LAYER  3      // only the last layer's weights affect the output
#define NACT   436
#define BATCH  256
#define NHEADS 18

// vout[j] = dot(wv_row_j, vsum) + bv[j], where vsum = sum over heads of val_p[3,0,h,:]
__global__ __launch_bounds__(64) void k_vvec(const float* __restrict__ in_proj_w,
                                             const float* __restrict__ in_proj_b,
                                             const float* __restrict__ val_p,
                                             float* __restrict__ vout) {
    __shared__ float vsum[EMB];
    const int t = threadIdx.x;
    const int j = blockIdx.x;
    const float* vp = val_p + (size_t)LAYER * NHEADS * EMB;
    for (int d = t; d < EMB; d += 64) {
        float s = 0.f;
        #pragma unroll
        for (int h = 0; h < NHEADS; ++h) s += vp[h * EMB + d];
        vsum[d] = s;
    }
    __syncthreads();
    // wv = rows [2*EMB, 3*EMB) of in_proj_w[LAYER]
    const float* row = in_proj_w + (size_t)LAYER * 3 * EMB * EMB + (size_t)(2 * EMB + j) * EMB;
    float p = 0.f;
    for (int d = t; d < EMB; d += 64) p += row[d] * vsum[d];
    #pragma unroll
    for (int off = 32; off > 0; off >>= 1) p += __shfl_xor(p, off);
    if (t == 0) vout[j] = p + in_proj_b[(size_t)LAYER * 3 * EMB + 2 * EMB + j];
}

// vout[j] = act(dot(W[LAYER] row j, vin) + b[LAYER][j])
__global__ __launch_bounds__(64) void k_matvec(const float* __restrict__ W,
                                               const float* __restrict__ b,
                                               const float* __restrict__ vin,
                                               float* __restrict__ vout,
                                               int relu_flag) {
    const int t = threadIdx.x;
    const int j = blockIdx.x;
    const float* row = W + (size_t)LAYER * EMB * EMB + (size_t)j * EMB;
    float p = 0.f;
    for (int d = t; d < EMB; d += 64) p += row[d] * vin[d];
    #pragma unroll
    for (int off = 32; off > 0; off >>= 1) p += __shfl_xor(p, off);
    if (t == 0) {
        float v = p + b[(size_t)LAYER * EMB + j];
        if (relu_flag) v = fmaxf(v, 0.f);
        vout[j] = v;
    }
}

// Each of 256 blocks redundantly computes softmax(alpha*r + beta) over the
// first NACT entries and writes its own FLOAT32 output row.
__global__ __launch_bounds__(512) void k_softmax_bcast(const float* __restrict__ r,
                                                       const float* __restrict__ bn_g,
                                                       const float* __restrict__ bn_b,
                                                       float* __restrict__ out) {
    __shared__ float red[512];
    const int t = threadIdx.x;
    const float inv_bn = 1.0f / sqrtf(1.0f + 1e-5f);
    const float alpha  = bn_g[LAYER * 63 + 0] * inv_bn;
    const float beta   = bn_b[LAYER * 63 + 0];

    float v = (t < NACT) ? fmaf(alpha, r[t], beta) : -3.4e38f;

    // block max
    red[t] = v; __syncthreads();
    #pragma unroll
    for (int s = 256; s > 0; s >>= 1) {
        if (t < s) red[t] = fmaxf(red[t], red[t + s]);
        __syncthreads();
    }
    const float mx = red[0];
    __syncthreads();

    float e = (t < NACT) ? expf(v - mx) : 0.f;
    red[t] = e; __syncthreads();
    #pragma unroll
    for (int s = 256; s > 0; s >>= 1) {
        if (t < s) red[t] += red[t + s];
        __syncthreads();
    }
    const float p = e / red[0];

    if (t < NACT) out[(size_t)blockIdx.x * NACT + t] = p;
}

extern "C" void kernel_launch(void* const* d_in, const int* in_sizes, int n_in,
                              void* d_out, int out_size, void* d_ws, size_t ws_size,
                              hipStream_t stream) {
    // setup_inputs() order:
    // 0:x 1:card_table 2:pe 3:in_proj_w 4:in_proj_b 5:out_w 6:out_b
    // 7:lin_w 8:lin_b 9:bn_g 10:bn_b 11:key_p 12:val_p
    const float* in_proj_w = (const float*)d_in[3];
    const float* in_proj_b = (const float*)d_in[4];
    const float* out_w     = (const float*)d_in[5];
    const float* out_b     = (const float*)d_in[6];
    const float* lin_w     = (const float*)d_in[7];
    const float* lin_b     = (const float*)d_in[8];
    const float* bn_g      = (const float*)d_in[9];
    const float* bn_b      = (const float*)d_in[10];
    const float* val_p     = (const float*)d_in[12];

    float* wsf = (float*)d_ws;      // [0,450): vvec  [450,900): c  [900,1350): r

    k_vvec  <<<EMB, 64, 0, stream>>>(in_proj_w, in_proj_b, val_p, wsf);
    k_matvec<<<EMB, 64, 0, stream>>>(out_w, out_b, wsf,        wsf + EMB,   0);
    k_matvec<<<EMB, 64, 0, stream>>>(lin_w, lin_b, wsf + EMB,  wsf + 2*EMB, 1);
    k_softmax_bcast<<<BATCH, 512, 0, stream>>>(wsf + 2*EMB, bn_g, bn_b,
                                               (float*)d_out);
}